// Round 18
// baseline (54.803 us; speedup 1.0000x reference)
//
#include <hip/hip_runtime.h>

// Window attention, b=8 s=4094 nh=8 h=64, radius 63, f32 I/O.
// Round 18 = r17 (best, 51.2us) + V-latency hiding by reordering:
//  - barrier-1 moved to right after the QK MFMA loop (K tile is dead
//    there; softmax is register-only, so this is legal);
//  - phase C (V staging) interleaved with the softmax in 3 batches:
//    {issue 4 V f32x4 loads -> softmax third (12 exp2) -> cvt+ds_write}.
//    Each batch's HBM/L2 latency hides under independent VALU instead of
//    sitting serial between softmax and PV. No extra VGPR held.
// Everything else verbatim r17: 512-thr blocks / 128 q / wave=16 q,
// K [256][64] bf16 (b128-staged, uniform banks) reused as V^T [64][272]
// (b64 i-permuted writes), no-max exp2 softmax, deferred 1/d, XCD swizzle,
// setprio around MFMA clusters, launch_bounds(512,4).
//
// MFMA 16x16x32 bf16 layouts (verified rounds 1-17):
//   A: lane l holds A[row=l&15][k=(l>>4)*8+j]   B: B[k=(l>>4)*8+j][col=l&15]
//   D: lane l reg r holds D[row=(l>>4)*4+r][col=l&15]

#define S_LEN 4094
#define NHEAD 8
#define HDIM  64
#define ROWSTR 512
#define KTILE 256            // staged K rows (keys)
#define VTILE 272            // staged V^T cols (keys)

typedef float f32x4 __attribute__((ext_vector_type(4)));
typedef short s16x8 __attribute__((ext_vector_type(8)));
typedef int   i32x2 __attribute__((ext_vector_type(2)));
typedef int   i32x4 __attribute__((ext_vector_type(4)));

#define QSCALE 0.1803368801f   // 0.125 * log2(e)

static __device__ __forceinline__ unsigned cvt_pk(float lo, float hi) {
    unsigned r;
    asm("v_cvt_pk_bf16_f32 %0, %1, %2" : "=v"(r) : "v"(lo), "v"(hi));
    return r;
}

// K view: [256 keys][64 h] bf16, row 128 B, swizzle ^((key&7)<<4)
static __device__ __forceinline__ int koff(int kr, int h) {
    return ((kr << 7) + (h << 1)) ^ ((kr & 7) << 4);
}
// V^T view: [64 h][272 keys] bf16, row 544 B, swizzle ^((h&7)<<4)
static __device__ __forceinline__ int voff(int h, int kc) {
    return (h * (VTILE * 2) + (kc << 1)) ^ ((h & 7) << 4);
}

static __device__ __forceinline__ f32x4 gload(const float* p, bool ok) {
    f32x4 x = {0.f, 0.f, 0.f, 0.f};
    if (ok) x = *(const f32x4*)p;
    return x;
}

static __device__ __forceinline__ s16x8 pack8(f32x4 x0, f32x4 x1) {
    i32x4 wd;
    wd[0] = (int)cvt_pk(x0[0], x0[1]); wd[1] = (int)cvt_pk(x0[2], x0[3]);
    wd[2] = (int)cvt_pk(x1[0], x1[1]); wd[3] = (int)cvt_pk(x1[2], x1[3]);
    return __builtin_bit_cast(s16x8, wd);
}

__global__ __launch_bounds__(512, 4)
void win_attn(const float* __restrict__ q, const float* __restrict__ k,
              const float* __restrict__ v, float* __restrict__ out)
{
    __shared__ __align__(16) short Tile[64 * VTILE + 64];   // 34.9 KiB, K then V^T

    const int tid  = threadIdx.x;
    const int lane = tid & 63;
    const int w    = tid >> 6;      // wave 0..7
    const int u    = lane >> 4;
    const int c16  = lane & 15;

    // ---- T1: XCD-bijective swizzle (2048 = 8 XCD x 256 contiguous) ----
    const int wg  = (int)blockIdx.x;
    const int swz = (wg & 7) * 256 + (wg >> 3);
    const int cx  = swz & 31;          // q-chunk 0..31
    const int rem = swz >> 5;
    const int hn  = rem & 7;           // head
    const int bz  = rem >> 3;          // batch

    const int q0 = cx * 128;
    const int g0 = q0 - 63;                      // key of tile index 0
    const int qw = q0 + w * 16;                  // this wave's first query
    const size_t bn = (size_t)bz * (S_LEN * ROWSTR) + (size_t)hn * HDIM;
    const float* qg = q + bn;
    const float* kg = k + bn;
    const float* vg = v + bn;

    // ---- Q loads issued first (hide under K staging) ----
    f32x4 qld[4];
    {
        int qr = qw + c16; if (qr > S_LEN - 1) qr = S_LEN - 1;
        const float* qp = qg + (size_t)qr * ROWSTR + u * 8;
        qld[0] = *(const f32x4*)(qp);
        qld[1] = *(const f32x4*)(qp + 4);
        qld[2] = *(const f32x4*)(qp + 32);
        qld[3] = *(const f32x4*)(qp + 36);
    }

    // ---- phase A: stage K. 256 rows x 8 h-octs = 2048 units, 4/thread.
    //      b128 writes, bank start 4*(ho^(kr&7)): uniform 8-deep. ----
    #pragma unroll
    for (int p = 0; p < 4; ++p) {
        int unit = p * 512 + tid;
        int kr = unit >> 3, ho = unit & 7;
        int g  = g0 + kr;
        bool ok = (g >= 0) && (g < S_LEN);
        const float* kp = kg + (size_t)g * ROWSTR + ho * 8;
        f32x4 x0 = gload(kp, ok);
        f32x4 x1 = gload(kp + 4, ok);
        i32x4 wd;
        wd[0] = (int)cvt_pk(x0[0], x0[1]); wd[1] = (int)cvt_pk(x0[2], x0[3]);
        wd[2] = (int)cvt_pk(x1[0], x1[1]); wd[3] = (int)cvt_pk(x1[2], x1[3]);
        *(i32x4*)((char*)Tile + koff(kr, ho * 8)) = wd;
    }
    __syncthreads();   // K tile ready

    // ---- phase B: QK^T (9 tiles) ----
    s16x8 bq[2];
    #pragma unroll
    for (int hf = 0; hf < 2; ++hf) {
        f32x4 x0 = qld[hf * 2]     * QSCALE;
        f32x4 x1 = qld[hf * 2 + 1] * QSCALE;
        bq[hf] = pack8(x0, x1);
    }

    f32x4 sc[9];
    __builtin_amdgcn_s_setprio(1);
    #pragma unroll
    for (int j = 0; j < 9; ++j) {
        int krow = w * 16 + j * 16 + c16;   // <= 255
        s16x8 ka0 = *(const s16x8*)((const char*)Tile + koff(krow, u * 8));
        s16x8 ka1 = *(const s16x8*)((const char*)Tile + koff(krow, 32 + u * 8));
        f32x4 acc = {0.f, 0.f, 0.f, 0.f};
        acc = __builtin_amdgcn_mfma_f32_16x16x32_bf16(ka0, bq[0], acc, 0, 0, 0);
        acc = __builtin_amdgcn_mfma_f32_16x16x32_bf16(ka1, bq[1], acc, 0, 0, 0);
        sc[j] = acc;
    }
    __builtin_amdgcn_s_setprio(0);
    __syncthreads();   // K tile DEAD here -- V^T staging may begin

    // ---- phase C + softmax interleaved: 3 batches of
    //      {issue 4 V f32x4 loads -> softmax third -> cvt+ds_write} ----
    const int iq = c16;
    float d = 0.f;
    #pragma unroll
    for (int p = 0; p < 3; ++p) {
        // issue this batch's V loads (unit = p*512+tid; 1088 units total)
        int unit = p * 512 + tid;
        bool act = unit < (VTILE / 4) * 16;
        int kq = unit >> 4, hq = unit & 15;
        int g  = g0 + kq * 4;
        f32x4 y0 = {0,0,0,0}, y1 = {0,0,0,0}, y2 = {0,0,0,0}, y3 = {0,0,0,0};
        if (act) {
            y0 = gload(vg + (size_t)(g + 0) * ROWSTR + hq * 4, g + 0 >= 0 && g + 0 < S_LEN);
            y1 = gload(vg + (size_t)(g + 1) * ROWSTR + hq * 4, g + 1 >= 0 && g + 1 < S_LEN);
            y2 = gload(vg + (size_t)(g + 2) * ROWSTR + hq * 4, g + 2 >= 0 && g + 2 < S_LEN);
            y3 = gload(vg + (size_t)(g + 3) * ROWSTR + hq * 4, g + 3 >= 0 && g + 3 < S_LEN);
        }
        // softmax third (register-only; hides the loads' latency)
        #pragma unroll
        for (int jj = 0; jj < 3; ++jj) {
            const int j = p * 3 + jj;
            #pragma unroll
            for (int r = 0; r < 4; ++r) {
                float s = sc[j][r];
                if (j == 0 || j >= 7) {   // only tiles 0,7,8 can violate the band
                    int tl = j * 16 + u * 4 + r;
                    bool inb = (tl >= iq) && (tl <= iq + 126);
                    s = inb ? s : -__builtin_inff();
                }
                float pv = __builtin_amdgcn_exp2f(s);   // 2^s; 2^-inf = 0
                sc[j][r] = pv;
                d += pv;
            }
        }
        // write this batch's V^T (b64, i-permuted -- r13's verified pattern)
        if (act) {
            #pragma unroll
            for (int ii = 0; ii < 4; ++ii) {
                int i = (ii + (hq >> 1)) & 3;        // spread h&7 across lanes
                int h = hq * 4 + i;
                i32x2 wd;
                wd[0] = (int)cvt_pk(y0[i], y1[i]);
                wd[1] = (int)cvt_pk(y2[i], y3[i]);
                *(i32x2*)((char*)Tile + voff(h, kq * 4)) = wd;
            }
        }
    }

    // ---- P pack (unnormalized) + d-reduce; 1/d deferred to epilogue ----
    int w0[9], w1[9];
    #pragma unroll
    for (int j = 0; j < 9; ++j) {
        w0[j] = (int)cvt_pk(sc[j][0], sc[j][1]);
        w1[j] = (int)cvt_pk(sc[j][2], sc[j][3]);
    }
    d += __shfl_xor(d, 16, 64);
    d += __shfl_xor(d, 32, 64);
    const float rdv = 1.f / d;
    __syncthreads();   // V^T ready

    // ---- phase D: P -> A-frags (shuffles) + PV + 1/d + stores ----
    const int sA = ((u & 1) * 2) * 16 + c16;
    const int sB = sA + 16;
    const bool hiHalf = (u >> 1) != 0;

    s16x8 pa[5];
    #pragma unroll
    for (int kf = 0; kf < 5; ++kf) {
        const int jtA = 2 * kf;        // tile feeding dest u<2 (0..8)
        const int jtB = 2 * kf + 1;    // tile feeding dest u>=2 (9 -> zero)
        int a0, a1, b0, b1;
        int e0 = 0, e1 = 0, f0 = 0, f1 = 0;
        a0 = __shfl(w0[jtA], sA, 64); a1 = __shfl(w1[jtA], sA, 64);
        b0 = __shfl(w0[jtA], sB, 64); b1 = __shfl(w1[jtA], sB, 64);
        if (jtB <= 8) {
            e0 = __shfl(w0[jtB], sA, 64); e1 = __shfl(w1[jtB], sA, 64);
            f0 = __shfl(w0[jtB], sB, 64); f1 = __shfl(w1[jtB], sB, 64);
        }
        i32x4 wd;
        wd[0] = hiHalf ? e0 : a0;
        wd[1] = hiHalf ? e1 : a1;
        wd[2] = hiHalf ? f0 : b0;
        wd[3] = hiHalf ? f1 : b1;
        pa[kf] = __builtin_bit_cast(s16x8, wd);
    }

    // fetch 1/d for this lane's 4 output rows (queries u*4+r)
    float rq[4];
    #pragma unroll
    for (int r = 0; r < 4; ++r)
        rq[r] = __shfl(rdv, u * 4 + r, 64);

    __builtin_amdgcn_s_setprio(1);
    #pragma unroll
    for (int ht = 0; ht < 4; ++ht) {
        f32x4 o = {0.f, 0.f, 0.f, 0.f};
        #pragma unroll
        for (int kf = 0; kf < 5; ++kf) {
            s16x8 bv = *(const s16x8*)((const char*)Tile +
                         voff(ht * 16 + c16, w * 16 + kf * 32 + u * 8));   // col <= 264
            o = __builtin_amdgcn_mfma_f32_16x16x32_bf16(pa[kf], bv, o, 0, 0, 0);
        }
        #pragma unroll
        for (int r = 0; r < 4; ++r) {
            int p = qw + u * 4 + r;
            if (p < S_LEN)
                out[bn + (size_t)p * ROWSTR + ht * 16 + c16] = o[r] * rq[r];
        }
    }
    __builtin_amdgcn_s_setprio(0);
}

extern "C" void kernel_launch(void* const* d_in, const int* in_sizes, int n_in,
                              void* d_out, int out_size, void* d_ws, size_t ws_size,
                              hipStream_t stream) {
    const float* q = (const float*)d_in[0];
    const float* k = (const float*)d_in[1];
    const float* v = (const float*)d_in[2];
    float* o = (float*)d_out;
    const int B = in_sizes[0] / (S_LEN * NHEAD * HDIM);
    dim3 grid(32 * NHEAD * B);   // 2048 blocks, XCD-swizzled in-kernel
    win_attn<<<grid, dim3(512), 0, stream>>>(q, k, v, o);
}

// Round 19
// 51.272 us; speedup vs baseline: 1.0689x; 1.0689x over previous
//
#include <hip/hip_runtime.h>

// Window attention, b=8 s=4094 nh=8 h=64, radius 63, f32 I/O.
// Round 19 = REVERT to round 17 (measured best: 51.2us, absmax 0.0156).
// r18's V/softmax interleave regressed (-7%): per-batch VALU (~60-100cy)
// can't hide ~300-500cy V latency; aligned stalls dropped occupancy 72->40%.
//
// Final configuration (18-round lever map):
//  - 512-thr blocks / 128 q; wave owns 16 q (32 waves/CU at 4 blocks).
//  - Two-phase 34.9 KiB LDS tile: K [256][64] bf16 (b128-staged, uniform
//    banks, swizzle ^((key&7)<<4)) reused as V^T [64][272] bf16 (b64
//    i-permuted writes, swizzle ^((h&7)<<4)).
//  - Swapped QK^T (S^T = K*Q^T): softmax row is lane-local; 2 shfl_xor
//    for the d-reduce; no-max exp2 softmax (|s|<~6 -> exact); 1/d deferred.
//  - P distributed to PV A-frags via 40 shfl of cvt_pk'd pairs.
//  - XCD-bijective block swizzle; s_setprio(1) around MFMA clusters.
//
// MFMA 16x16x32 bf16 layouts (verified rounds 1-18):
//   A: lane l holds A[row=l&15][k=(l>>4)*8+j]   B: B[k=(l>>4)*8+j][col=l&15]
//   D: lane l reg r holds D[row=(l>>4)*4+r][col=l&15]

#define S_LEN 4094
#define NHEAD 8
#define HDIM  64
#define ROWSTR 512
#define KTILE 256            // staged K rows (keys)
#define VTILE 272            // staged V^T cols (keys)

typedef float f32x4 __attribute__((ext_vector_type(4)));
typedef short s16x8 __attribute__((ext_vector_type(8)));
typedef int   i32x2 __attribute__((ext_vector_type(2)));
typedef int   i32x4 __attribute__((ext_vector_type(4)));

#define QSCALE 0.1803368801f   // 0.125 * log2(e)

static __device__ __forceinline__ unsigned cvt_pk(float lo, float hi) {
    unsigned r;
    asm("v_cvt_pk_bf16_f32 %0, %1, %2" : "=v"(r) : "v"(lo), "v"(hi));
    return r;
}

// K view: [256 keys][64 h] bf16, row 128 B, swizzle ^((key&7)<<4)
static __device__ __forceinline__ int koff(int kr, int h) {
    return ((kr << 7) + (h << 1)) ^ ((kr & 7) << 4);
}
// V^T view: [64 h][272 keys] bf16, row 544 B, swizzle ^((h&7)<<4)
static __device__ __forceinline__ int voff(int h, int kc) {
    return (h * (VTILE * 2) + (kc << 1)) ^ ((h & 7) << 4);
}

static __device__ __forceinline__ f32x4 gload(const float* p, bool ok) {
    f32x4 x = {0.f, 0.f, 0.f, 0.f};
    if (ok) x = *(const f32x4*)p;
    return x;
}

static __device__ __forceinline__ s16x8 pack8(f32x4 x0, f32x4 x1) {
    i32x4 wd;
    wd[0] = (int)cvt_pk(x0[0], x0[1]); wd[1] = (int)cvt_pk(x0[2], x0[3]);
    wd[2] = (int)cvt_pk(x1[0], x1[1]); wd[3] = (int)cvt_pk(x1[2], x1[3]);
    return __builtin_bit_cast(s16x8, wd);
}

__global__ __launch_bounds__(512, 4)
void win_attn(const float* __restrict__ q, const float* __restrict__ k,
              const float* __restrict__ v, float* __restrict__ out)
{
    __shared__ __align__(16) short Tile[64 * VTILE + 64];   // 34.9 KiB, K then V^T

    const int tid  = threadIdx.x;
    const int lane = tid & 63;
    const int w    = tid >> 6;      // wave 0..7
    const int u    = lane >> 4;
    const int c16  = lane & 15;

    // ---- T1: XCD-bijective swizzle (2048 = 8 XCD x 256 contiguous) ----
    const int wg  = (int)blockIdx.x;
    const int swz = (wg & 7) * 256 + (wg >> 3);
    const int cx  = swz & 31;          // q-chunk 0..31
    const int rem = swz >> 5;
    const int hn  = rem & 7;           // head
    const int bz  = rem >> 3;          // batch

    const int q0 = cx * 128;
    const int g0 = q0 - 63;                      // key of tile index 0
    const int qw = q0 + w * 16;                  // this wave's first query
    const size_t bn = (size_t)bz * (S_LEN * ROWSTR) + (size_t)hn * HDIM;
    const float* qg = q + bn;
    const float* kg = k + bn;
    const float* vg = v + bn;

    // ---- Q loads issued first (hide under K staging) ----
    f32x4 qld[4];
    {
        int qr = qw + c16; if (qr > S_LEN - 1) qr = S_LEN - 1;
        const float* qp = qg + (size_t)qr * ROWSTR + u * 8;
        qld[0] = *(const f32x4*)(qp);
        qld[1] = *(const f32x4*)(qp + 4);
        qld[2] = *(const f32x4*)(qp + 32);
        qld[3] = *(const f32x4*)(qp + 36);
    }

    // ---- phase A: stage K. 256 rows x 8 h-octs = 2048 units, 4/thread.
    //      b128 writes, bank start 4*(ho^(kr&7)): uniform 8-deep. ----
    #pragma unroll
    for (int p = 0; p < 4; ++p) {
        int unit = p * 512 + tid;
        int kr = unit >> 3, ho = unit & 7;
        int g  = g0 + kr;
        bool ok = (g >= 0) && (g < S_LEN);
        const float* kp = kg + (size_t)g * ROWSTR + ho * 8;
        f32x4 x0 = gload(kp, ok);
        f32x4 x1 = gload(kp + 4, ok);
        i32x4 wd;
        wd[0] = (int)cvt_pk(x0[0], x0[1]); wd[1] = (int)cvt_pk(x0[2], x0[3]);
        wd[2] = (int)cvt_pk(x1[0], x1[1]); wd[3] = (int)cvt_pk(x1[2], x1[3]);
        *(i32x4*)((char*)Tile + koff(kr, ho * 8)) = wd;
    }
    __syncthreads();   // K tile ready

    // ---- phase B: QK^T (9 tiles) + no-max exp2 softmax; P packed to regs ----
    s16x8 bq[2];
    #pragma unroll
    for (int hf = 0; hf < 2; ++hf) {
        f32x4 x0 = qld[hf * 2]     * QSCALE;
        f32x4 x1 = qld[hf * 2 + 1] * QSCALE;
        bq[hf] = pack8(x0, x1);
    }

    f32x4 sc[9];
    __builtin_amdgcn_s_setprio(1);
    #pragma unroll
    for (int j = 0; j < 9; ++j) {
        int krow = w * 16 + j * 16 + c16;   // <= 255
        s16x8 ka0 = *(const s16x8*)((const char*)Tile + koff(krow, u * 8));
        s16x8 ka1 = *(const s16x8*)((const char*)Tile + koff(krow, 32 + u * 8));
        f32x4 acc = {0.f, 0.f, 0.f, 0.f};
        acc = __builtin_amdgcn_mfma_f32_16x16x32_bf16(ka0, bq[0], acc, 0, 0, 0);
        acc = __builtin_amdgcn_mfma_f32_16x16x32_bf16(ka1, bq[1], acc, 0, 0, 0);
        sc[j] = acc;
    }
    __builtin_amdgcn_s_setprio(0);

    // band mask (only tiles 0,7,8 can violate); exp2; P pack; 1/d deferred
    const int iq = c16;
    float d = 0.f;
    int w0[9], w1[9];
    #pragma unroll
    for (int j = 0; j < 9; ++j) {
        #pragma unroll
        for (int r = 0; r < 4; ++r) {
            float s = sc[j][r];
            if (j == 0 || j >= 7) {
                int tl = j * 16 + u * 4 + r;
                bool inb = (tl >= iq) && (tl <= iq + 126);
                s = inb ? s : -__builtin_inff();
            }
            float pv = __builtin_amdgcn_exp2f(s);   // 2^s; 2^-inf = 0
            sc[j][r] = pv;
            d += pv;
        }
    }
    #pragma unroll
    for (int j = 0; j < 9; ++j) {
        w0[j] = (int)cvt_pk(sc[j][0], sc[j][1]);
        w1[j] = (int)cvt_pk(sc[j][2], sc[j][3]);
    }
    d += __shfl_xor(d, 16, 64);
    d += __shfl_xor(d, 32, 64);
    const float rdv = 1.f / d;
    __syncthreads();   // all waves done reading K tile

    // ---- phase C: stage V^T (68 key-quads x 16 h-quads = 1088 units),
    //      b64 writes with i-permutation (r13's verified pattern) ----
    #pragma unroll
    for (int p = 0; p < 3; ++p) {
        int unit = p * 512 + tid;
        if (unit < (VTILE / 4) * 16) {
            int kq = unit >> 4, hq = unit & 15;
            int g  = g0 + kq * 4;
            f32x4 y0 = gload(vg + (size_t)(g + 0) * ROWSTR + hq * 4, g + 0 >= 0 && g + 0 < S_LEN);
            f32x4 y1 = gload(vg + (size_t)(g + 1) * ROWSTR + hq * 4, g + 1 >= 0 && g + 1 < S_LEN);
            f32x4 y2 = gload(vg + (size_t)(g + 2) * ROWSTR + hq * 4, g + 2 >= 0 && g + 2 < S_LEN);
            f32x4 y3 = gload(vg + (size_t)(g + 3) * ROWSTR + hq * 4, g + 3 >= 0 && g + 3 < S_LEN);
            #pragma unroll
            for (int ii = 0; ii < 4; ++ii) {
                int i = (ii + (hq >> 1)) & 3;        // spread h&7 across lanes
                int h = hq * 4 + i;
                i32x2 wd;
                wd[0] = (int)cvt_pk(y0[i], y1[i]);
                wd[1] = (int)cvt_pk(y2[i], y3[i]);
                *(i32x2*)((char*)Tile + voff(h, kq * 4)) = wd;
            }
        }
    }
    __syncthreads();   // V^T ready

    // ---- phase D: P -> A-frags (shuffles) + PV + 1/d + stores ----
    const int sA = ((u & 1) * 2) * 16 + c16;
    const int sB = sA + 16;
    const bool hiHalf = (u >> 1) != 0;

    s16x8 pa[5];
    #pragma unroll
    for (int kf = 0; kf < 5; ++kf) {
        const int jtA = 2 * kf;        // tile feeding dest u<2 (0..8)
        const int jtB = 2 * kf + 1;    // tile feeding dest u>=2 (9 -> zero)
        int a0, a1, b0, b1;
        int e0 = 0, e1 = 0, f0 = 0, f1 = 0;
        a0 = __shfl(w0[jtA], sA, 64); a1 = __shfl(w1[jtA], sA, 64);
        b0 = __shfl(w0[jtA], sB, 64); b1 = __shfl(w1[jtA], sB, 64);
        if (jtB <= 8) {
            e0 = __shfl(w0[jtB], sA, 64); e1 = __shfl(w1[jtB], sA, 64);
            f0 = __shfl(w0[jtB], sB, 64); f1 = __shfl(w1[jtB], sB, 64);
        }
        i32x4 wd;
        wd[0] = hiHalf ? e0 : a0;
        wd[1] = hiHalf ? e1 : a1;
        wd[2] = hiHalf ? f0 : b0;
        wd[3] = hiHalf ? f1 : b1;
        pa[kf] = __builtin_bit_cast(s16x8, wd);
    }

    // fetch 1/d for this lane's 4 output rows (queries u*4+r)
    float rq[4];
    #pragma unroll
    for (int r = 0; r < 4; ++r)
        rq[r] = __shfl(rdv, u * 4 + r, 64);

    __builtin_amdgcn_s_setprio(1);
    #pragma unroll
    for (int ht = 0; ht < 4; ++ht) {
        f32x4 o = {0.f, 0.f, 0.f, 0.f};
        #pragma unroll
        for (int kf = 0; kf < 5; ++kf) {
            s16x8 bv = *(const s16x8*)((const char*)Tile +
                         voff(ht * 16 + c16, w * 16 + kf * 32 + u * 8));   // col <= 264
            o = __builtin_amdgcn_mfma_f32_16x16x32_bf16(pa[kf], bv, o, 0, 0, 0);
        }
        #pragma unroll
        for (int r = 0; r < 4; ++r) {
            int p = qw + u * 4 + r;
            if (p < S_LEN)
                out[bn + (size_t)p * ROWSTR + ht * 16 + c16] = o[r] * rq[r];
        }
    }
    __builtin_amdgcn_s_setprio(0);
}

extern "C" void kernel_launch(void* const* d_in, const int* in_sizes, int n_in,
                              void* d_out, int out_size, void* d_ws, size_t ws_size,
                              hipStream_t stream) {
    const float* q = (const float*)d_in[0];
    const float* k = (const float*)d_in[1];
    const float* v = (const float*)d_in[2];
    float* o = (float*)d_out;
    const int B = in_sizes[0] / (S_LEN * NHEAD * HDIM);
    dim3 grid(32 * NHEAD * B);   // 2048 blocks, XCD-swizzled in-kernel
    win_attn<<<grid, dim3(512), 0, stream>>>(q, k, v, o);
}